// Round 1
// baseline (201.104 us; speedup 1.0000x reference)
//
#include <hip/hip_runtime.h>
#include <math.h>

#define EPS 1e-7f
#define REG_MAX 16
#define NC 80
#define A_DIM 8400

// ws layout (floats): [0]=sum_loss_iou_numer, [1]=sum_dfl, [2]=num_fg
__global__ __launch_bounds__(256) void bbox_loss_main(
    const float* __restrict__ pred_dist,      // (B,A,64)
    const float* __restrict__ pred_bboxes,    // (B,A,4)
    const float* __restrict__ anchor_points,  // (A,2)
    const float* __restrict__ target_bboxes,  // (B,A,4)
    const float* __restrict__ target_scores,  // (B,A,80)
    const int*   __restrict__ fg_mask,        // (B,A) int32
    float* __restrict__ acc)
{
    const int i = blockIdx.x * blockDim.x + threadIdx.x;  // pair index, grid exactly covers B*A

    float liou = 0.f, ldfl = 0.f, nfg = 0.f;

    if (fg_mask[i] != 0) {
        nfg = 1.f;
        const int a = i % A_DIM;
        const float ax = anchor_points[2 * a + 0];
        const float ay = anchor_points[2 * a + 1];

        const float4 pb = *(const float4*)(pred_bboxes + (size_t)i * 4);
        const float4 tb = *(const float4*)(target_bboxes + (size_t)i * 4);

        // ---- weight = sum of 80 class scores ----
        const float4* ts = (const float4*)(target_scores + (size_t)i * NC);
        float w = 0.f;
        #pragma unroll
        for (int k = 0; k < NC / 4; ++k) {
            float4 v = ts[k];
            w += v.x + v.y + v.z + v.w;
        }

        // ---- CIoU ----
        const float x11 = pb.x, y11 = pb.y, x21 = pb.z, y21 = pb.w;
        const float x12 = tb.x, y12 = tb.y, x22 = tb.z, y22 = tb.w;
        const float iw = fmaxf(fminf(x21, x22) - fmaxf(x11, x12), 0.f);
        const float ih = fmaxf(fminf(y21, y22) - fmaxf(y11, y12), 0.f);
        const float inter = iw * ih;
        const float w1 = x21 - x11, h1 = y21 - y11;
        const float w2 = x22 - x12, h2 = y22 - y12;
        const float uni = w1 * h1 + w2 * h2 - inter + EPS;
        const float iou = inter / uni;
        const float cw = fmaxf(x21, x22) - fminf(x11, x12);
        const float ch = fmaxf(y21, y22) - fminf(y11, y12);
        const float c2 = cw * cw + ch * ch + EPS;
        const float dx = x11 + x21 - x12 - x22;
        const float dy = y11 + y21 - y12 - y22;
        const float rho2 = (dx * dx + dy * dy) * 0.25f;
        const float dang = atanf(w1 / (h1 + EPS)) - atanf(w2 / (h2 + EPS));
        const float v = (4.f / (float)(M_PI * M_PI)) * dang * dang;
        const float alpha = v / (1.f - iou + v + EPS);
        const float ciou = iou - (rho2 / c2 + v * alpha);
        liou = (1.f - ciou) * w;

        // ---- DFL ----
        float t[4];
        t[0] = fminf(fmaxf(ax - tb.x, 0.f), (float)(REG_MAX - 1) - 0.01f);
        t[1] = fminf(fmaxf(ay - tb.y, 0.f), (float)(REG_MAX - 1) - 0.01f);
        t[2] = fminf(fmaxf(tb.z - ax, 0.f), (float)(REG_MAX - 1) - 0.01f);
        t[3] = fminf(fmaxf(tb.w - ay, 0.f), (float)(REG_MAX - 1) - 0.01f);

        const float* pd = pred_dist + (size_t)i * (4 * REG_MAX);
        float dfl = 0.f;
        #pragma unroll
        for (int s = 0; s < 4; ++s) {
            float x[REG_MAX];
            const float4* p4 = (const float4*)(pd + s * REG_MAX);
            #pragma unroll
            for (int k = 0; k < REG_MAX / 4; ++k) {
                float4 vv = p4[k];
                x[4 * k + 0] = vv.x; x[4 * k + 1] = vv.y;
                x[4 * k + 2] = vv.z; x[4 * k + 3] = vv.w;
            }
            float m = x[0];
            #pragma unroll
            for (int k = 1; k < REG_MAX; ++k) m = fmaxf(m, x[k]);
            float se = 0.f;
            #pragma unroll
            for (int k = 0; k < REG_MAX; ++k) se += __expf(x[k] - m);
            const float lse = m + __logf(se);
            const int tl = (int)t[s];
            const int tr = min(tl + 1, REG_MAX - 1);
            const float wl = (float)(tl + 1) - t[s];
            const float wr = 1.f - wl;
            dfl += (lse - x[tl]) * wl + (lse - x[tr]) * wr;
        }
        ldfl = dfl;
    }

    // ---- reduction: wave (64) shuffle -> LDS -> one atomicAdd per block ----
    #pragma unroll
    for (int off = 32; off > 0; off >>= 1) {
        liou += __shfl_down(liou, off);
        ldfl += __shfl_down(ldfl, off);
        nfg  += __shfl_down(nfg, off);
    }
    __shared__ float s0[4], s1[4], s2[4];
    const int wave = threadIdx.x >> 6;
    const int lane = threadIdx.x & 63;
    if (lane == 0) { s0[wave] = liou; s1[wave] = ldfl; s2[wave] = nfg; }
    __syncthreads();
    if (threadIdx.x == 0) {
        float a0 = 0.f, a1 = 0.f, a2 = 0.f;
        #pragma unroll
        for (int k = 0; k < 4; ++k) { a0 += s0[k]; a1 += s1[k]; a2 += s2[k]; }
        atomicAdd(&acc[0], a0);
        atomicAdd(&acc[1], a1);
        atomicAdd(&acc[2], a2);
    }
}

__global__ void bbox_loss_finalize(const float* __restrict__ acc,
                                   const float* __restrict__ tss,
                                   float* __restrict__ out)
{
    out[0] = acc[0] / tss[0];
    out[1] = acc[1] / fmaxf(acc[2] * 4.f, 1.f);
}

extern "C" void kernel_launch(void* const* d_in, const int* in_sizes, int n_in,
                              void* d_out, int out_size, void* d_ws, size_t ws_size,
                              hipStream_t stream) {
    const float* pred_dist     = (const float*)d_in[0];
    const float* pred_bboxes   = (const float*)d_in[1];
    const float* anchor_points = (const float*)d_in[2];
    const float* target_bboxes = (const float*)d_in[3];
    const float* target_scores = (const float*)d_in[4];
    const float* tss           = (const float*)d_in[5];
    const int*   fg_mask       = (const int*)d_in[6];
    float* out = (float*)d_out;
    float* acc = (float*)d_ws;

    const int total = in_sizes[6];           // B*A = 268800
    const int block = 256;
    const int grid = (total + block - 1) / block;  // 1050, exact

    hipMemsetAsync(acc, 0, 3 * sizeof(float), stream);
    bbox_loss_main<<<grid, block, 0, stream>>>(pred_dist, pred_bboxes, anchor_points,
                                               target_bboxes, target_scores, fg_mask, acc);
    bbox_loss_finalize<<<1, 1, 0, stream>>>(acc, tss, out);
}